// Round 19
// baseline (128.527 us; speedup 1.0000x reference)
//
#include <hip/hip_runtime.h>
#include <hip/hip_bf16.h>
#include <math.h>

#define HD 128          // N_HEADS * OUT_FEATS
#define IN_F 256
#define NEG_SLOPE 0.2f
#define NMAX 50000      // problem-fixed node count (LDS histogram capacity)
#define GGRID 256       // uniform place+gemm grid (1 block/CU)
#define CSRC 32         // src-histogram chunk count (only totals needed)

typedef __attribute__((ext_vector_type(8))) short short8;
typedef __attribute__((ext_vector_type(4))) float f32x4;

__device__ __forceinline__ unsigned short f2bf(float x) {
    __hip_bfloat16 b = __float2bfloat16(x);
    return *(unsigned short*)&b;
}
__device__ __forceinline__ float bf2f(unsigned short u) {
    unsigned int v = ((unsigned int)u) << 16;
    float f;
    __builtin_memcpy(&f, &v, 4);
    return f;
}
__device__ __forceinline__ short8 pack8(float4 f0, float4 f1) {
    short8 v;
    v[0] = (short)f2bf(f0.x); v[1] = (short)f2bf(f0.y);
    v[2] = (short)f2bf(f0.z); v[3] = (short)f2bf(f0.w);
    v[4] = (short)f2bf(f1.x); v[5] = (short)f2bf(f1.y);
    v[6] = (short)f2bf(f1.z); v[7] = (short)f2bf(f1.w);
    return v;
}

// ======== K1: histograms + weight conversion + ew columns, one launch ========
__global__ __launch_bounds__(1024) void hist_cvt_kernel(
    const int* __restrict__ src, const int* __restrict__ dst,
    unsigned short* __restrict__ pc_src, unsigned short* __restrict__ pc_dst,
    const float4* __restrict__ wfc4, const float4* __restrict__ wres4,
    const float* __restrict__ wfc, const float* __restrict__ attn_l,
    const float* __restrict__ attn_r, ushort4* __restrict__ w16,
    unsigned short* __restrict__ ew16, int n4each,
    int N, int E, int C, int chunk, int chunk_s) {
    __shared__ unsigned int h[NMAX / 2];   // 100 KB packed uint16 counts
    int tid = threadIdx.x;
    int b = blockIdx.x;

    if (b >= C + CSRC) {
        int rb = b - C - CSRC;
        if (rb == 0) {
            int hh = tid >> 8, k = tid & 255;
            float sl = 0.f, sr = 0.f;
#pragma unroll 8
            for (int d = 0; d < 32; d++) {
                float w = wfc[(size_t)(hh * 32 + d) * IN_F + k];
                sl += attn_l[hh * 32 + d] * w;
                sr += attn_r[hh * 32 + d] * w;
            }
            ew16[hh * IN_F + k] = f2bf(sl);
            ew16[(4 + hh) * IN_F + k] = f2bf(sr);
            ew16[(8 + hh) * IN_F + k] = 0;
            ew16[(12 + hh) * IN_F + k] = 0;
        } else {
            int idx = (rb - 1) * 1024 + tid;
            if (idx < 2 * n4each) {
                float4 f = (idx < n4each) ? wfc4[idx] : wres4[idx - n4each];
                ushort4 u;
                u.x = f2bf(f.x); u.y = f2bf(f.y); u.z = f2bf(f.z); u.w = f2bf(f.w);
                w16[idx] = u;
            }
        }
        return;
    }

    int nh = N >> 1;                        // N even
    uint4* h4 = (uint4*)h;
    for (int i = tid; i < (nh >> 2); i += 1024) h4[i] = make_uint4(0, 0, 0, 0);
    for (int i = (nh & ~3) + tid; i < nh; i += 1024) h[i] = 0;
    __syncthreads();

    bool isSrc = (b >= C);
    const int* arr = isSrc ? src : dst;
    int c = isSrc ? (b - C) : b;
    int ch = isSrc ? chunk_s : chunk;
    int e0 = c * ch, e1 = min(E, (c + 1) * ch);
    for (int e = e0 + tid; e < e1; e += 1024) {
        int v = arr[e];
        atomicAdd(&h[v >> 1], 1u << ((v & 1) << 4));
    }
    __syncthreads();

    unsigned short* pc = (isSrc ? pc_src : pc_dst) + (size_t)c * N;
    uint4* pc4 = (uint4*)pc;
    for (int i = tid; i < (nh >> 2); i += 1024) pc4[i] = h4[i];
    for (int i = (nh & ~3) + tid; i < nh; i += 1024) ((unsigned int*)pc)[i] = h[i];
}

// ---------------- per-node chunk prefix (in place) + degrees + scan1 ----------------
__global__ __launch_bounds__(256) void sum_scan1_kernel(
    const unsigned short* __restrict__ pc_src, unsigned short* __restrict__ pc_dst,
    int* __restrict__ out_cnt, int* __restrict__ deg, int* __restrict__ bsum,
    int N, int C) {
    __shared__ int wsum[4];
    int n = blockIdx.x * 256 + threadIdx.x;
    int sd = 0;
    if (n < N) {
        int ss = 0;
#pragma unroll 4
        for (int c = 0; c < CSRC; c++) ss += pc_src[(size_t)c * N + n];
        for (int c = 0; c < C; c++) {
            unsigned short v = pc_dst[(size_t)c * N + n];
            pc_dst[(size_t)c * N + n] = (unsigned short)sd;  // exclusive chunk prefix
            sd += v;
        }
        out_cnt[n] = ss;
        deg[n] = sd;
    }
    int v = (n < N) ? sd : 0;
#pragma unroll
    for (int d = 1; d < 64; d <<= 1) v += __shfl_xor(v, d);
    if ((threadIdx.x & 63) == 0) wsum[threadIdx.x >> 6] = v;
    __syncthreads();
    if (threadIdx.x == 0) bsum[blockIdx.x] = wsum[0] + wsum[1] + wsum[2] + wsum[3];
}

// ---------------- scan3 with internal block-sum scan; also zeroes tilectr ----------
__global__ __launch_bounds__(256) void scan3_kernel(const int* __restrict__ deg,
                                                    const int* __restrict__ bsum,
                                                    int* __restrict__ row_start,
                                                    int* __restrict__ tilectr,
                                                    int N, int nb, int E) {
    __shared__ int wsum[4];
    __shared__ int sbo[256];
    int tid = threadIdx.x, lane = tid & 63, wid = tid >> 6;
    {
        int v = (tid < nb) ? bsum[tid] : 0;
        int incl = v;
#pragma unroll
        for (int d = 1; d < 64; d <<= 1) {
            int t = __shfl_up(incl, d);
            if (lane >= d) incl += t;
        }
        if (lane == 63) wsum[wid] = incl;
        __syncthreads();
        int woff = 0;
        for (int w = 0; w < wid; w++) woff += wsum[w];
        sbo[tid] = woff + incl - v;    // exclusive prefix of block sums
        __syncthreads();
    }
    int boff = sbo[blockIdx.x];
    if (blockIdx.x == 0 && tid == 0) {
        row_start[N] = E;
        *tilectr = 0;
    }
    __syncthreads();

    int i = blockIdx.x * 256 + tid;
    int v = (i < N) ? deg[i] : 0;
    int incl = v;
#pragma unroll
    for (int d = 1; d < 64; d <<= 1) {
        int t = __shfl_up(incl, d);
        if (lane >= d) incl += t;
    }
    if (lane == 63) wsum[wid] = incl;
    __syncthreads();
    int woff = 0;
    for (int w = 0; w < wid; w++) woff += wsum[w];
    int excl = boff + woff + incl - v;
    if (i < N) row_start[i] = excl;
}

// ======== K3: place (blocks < C) then GEMM, B in regs, 1 barrier/tile ========
// Uniform grid, 1 block/CU, 16 waves. Each wave's 16-col B panel lives in 8
// short8 VGPRs for the whole kernel (invariant across tiles). sA double-buffered
// + sT double-buffered tile stealing -> ONE barrier per tile; the steal and the
// A-prefetch both hide under the k-loop + epilogue. ew cols in sE (8 KiB LDS).
__global__ __launch_bounds__(1024, 1) void place_gemm_kernel(
    const int* __restrict__ src, const int* __restrict__ dst,
    const unsigned short* __restrict__ chunkpre, const int* __restrict__ row_start,
    int* __restrict__ esrc,
    const float* __restrict__ feat, const __hip_bfloat16* __restrict__ w16,
    const __hip_bfloat16* __restrict__ ew16, const int* __restrict__ out_cnt,
    unsigned short* __restrict__ h16, unsigned short* __restrict__ resid16,
    float* __restrict__ el, float* __restrict__ er, int* __restrict__ tilectr,
    int N, int E, int C, int chunk, int ntiles) {
    __shared__ __align__(16) char smem[102400];   // place cur (100 KB) | gemm 41 KB
    int tid = threadIdx.x;

    if ((int)blockIdx.x < C) {
        // ---------------- place phase ----------------
        unsigned int* cur = (unsigned int*)smem;   // packed uint16 cursors
        int nh = N >> 1;
        const unsigned short* cp = chunkpre + (size_t)blockIdx.x * N;
        const uint4* cp4 = (const uint4*)cp;
        uint4* cur4 = (uint4*)cur;
        for (int i = tid; i < (nh >> 2); i += 1024) cur4[i] = cp4[i];
        for (int i = (nh & ~3) + tid; i < nh; i += 1024)
            cur[i] = ((const unsigned int*)cp)[i];
        __syncthreads();

        int e1 = min(E, (int)(blockIdx.x + 1) * chunk);
        for (int e = blockIdx.x * chunk + tid; e < e1; e += 1024) {
            int d = dst[e], s = src[e];
            int sh = (d & 1) << 4;
            unsigned int old = atomicAdd(&cur[d >> 1], 1u << sh);
            int rank = (old >> sh) & 0xffff;
            esrc[row_start[d] + rank] = s;
        }
        __syncthreads();   // cursor table dead; smem reusable by gemm phase
    }

    // ---------------- gemm phase (all blocks) ----------------
    unsigned short* sA0 = (unsigned short*)smem;             // 16 KiB
    unsigned short* sA1 = (unsigned short*)(smem + 16384);   // 16 KiB
    unsigned short* sE  = (unsigned short*)(smem + 32768);   //  8 KiB
    int* sT = (int*)(smem + 40960);                          // 2-slot steal
    int lane = tid & 63, w = tid >> 6;        // 16 waves
    int l15 = lane & 15, lg = lane >> 4;
    int c0 = w * 16;
    bool w0 = (w == 0);
    bool isH = (w < 8);
    int colloc = c0 & 127;

    // B panel in regs: this wave's 16 cols x 256 K = 8 x short8 (32 VGPR)
    short8 breg[8];
    {
        const __hip_bfloat16* bp = w16 + (size_t)(c0 + l15) * IN_F + lg * 8;
#pragma unroll
        for (int kk = 0; kk < 8; kk++) breg[kk] = *(const short8*)(bp + kk * 32);
    }
    // stage sE (ew16, XOR-swizzled) — read only by wave 0 in the k-loop
    if (tid < 512) {
        int r = tid >> 5, g = tid & 31;
        short8 v = *(const short8*)(ew16 + r * IN_F + g * 8);
        *(short8*)&sE[r * 256 + ((g ^ (r & 7)) * 8)] = v;
    }

    int srow = tid >> 5, sgc = tid & 31;      // one A granule per thread

    if (tid == 0) sT[0] = atomicAdd(tilectr, 1);
    __syncthreads();
    int t = sT[0];
    float4 fA0, fA1;
    if (t < ntiles) {
        int gm = t * 32 + srow;
        gm = (gm < N) ? gm : (N - 1);
        const float4* fp = (const float4*)(feat + (size_t)gm * IN_F + sgc * 8);
        fA0 = fp[0];
        fA1 = fp[1];
    }
    if (tid == 0) sT[1] = atomicAdd(tilectr, 1);
    if (t < ntiles)
        *(short8*)&sA0[srow * 256 + ((sgc ^ (srow & 7)) * 8)] = pack8(fA0, fA1);
    __syncthreads();   // sA0 + sT[1] visible

    int p = 0;
    while (t < ntiles) {
        unsigned short* sAc = p ? sA1 : sA0;
        unsigned short* sAn = p ? sA0 : sA1;
        int tn = sT[p ^ 1];                       // stolen last iteration
        if (tn < ntiles) {                        // issue next tile's loads now
            int gm = tn * 32 + srow;
            gm = (gm < N) ? gm : (N - 1);
            const float4* fp = (const float4*)(feat + (size_t)gm * IN_F + sgc * 8);
            fA0 = fp[0];
            fA1 = fp[1];
        }
        if (tid == 0) sT[p] = atomicAdd(tilectr, 1);   // for iteration after next

        // ---- k-loop: 2 sA ds_reads + 2 MFMA per k-step (B in regs) ----
        f32x4 acc[2], accE[2];
#pragma unroll
        for (int i = 0; i < 2; i++) {
            acc[i] = (f32x4){0.f, 0.f, 0.f, 0.f};
            accE[i] = (f32x4){0.f, 0.f, 0.f, 0.f};
        }
#pragma unroll
        for (int kk = 0; kk < 8; kk++) {
            int gs = (kk * 4 + lg) ^ (l15 & 7);
            short8 a[2];
#pragma unroll
            for (int mi = 0; mi < 2; mi++)
                a[mi] = *(const short8*)&sAc[(mi * 16 + l15) * 256 + gs * 8];
#pragma unroll
            for (int mi = 0; mi < 2; mi++)
                acc[mi] = __builtin_amdgcn_mfma_f32_16x16x32_bf16(a[mi], breg[kk],
                                                                  acc[mi], 0, 0, 0);
            if (w0) {
                short8 be = *(const short8*)&sE[l15 * 256 + gs * 8];
#pragma unroll
                for (int mi = 0; mi < 2; mi++)
                    accE[mi] = __builtin_amdgcn_mfma_f32_16x16x32_bf16(
                        a[mi], be, accE[mi], 0, 0, 0);
            }
        }

        // ---- epilogue. C/D: col = lane&15, row = 4*(lane>>4)+reg ----
        int bm = t * 32;
#pragma unroll
        for (int mi = 0; mi < 2; mi++) {
#pragma unroll
            for (int reg = 0; reg < 4; reg++) {
                int r = bm + mi * 16 + lg * 4 + reg;
                bool valid = (r < N);
                int rr = valid ? r : 0;
                if (isH) {
                    float nrm = rsqrtf(fmaxf((float)out_cnt[rr], 1.0f));
                    if (valid) {
                        h16[(size_t)r * HD + colloc + l15] = f2bf(acc[mi][reg] * nrm);
                        if (w0) {
                            float ev = accE[mi][reg];  // l15<4: el, 4..7: er
                            if (l15 < 4) el[r * 4 + l15] = ev * nrm;
                            else if (l15 < 8) er[r * 4 + (l15 - 4)] = ev;
                        }
                    }
                } else if (valid) {
                    resid16[(size_t)r * HD + colloc + l15] = f2bf(acc[mi][reg]);
                }
            }
        }

        // ---- stage next tile into the other buffer (load waitcnt lands here) ----
        if (tn < ntiles)
            *(short8*)&sAn[srow * 256 + ((sgc ^ (srow & 7)) * 8)] = pack8(fA0, fA1);
        __syncthreads();   // sAn + sT[p] visible; sAc reads complete
        t = tn;
        p ^= 1;
    }
}

// ---------------- fused edge softmax + weighted scatter + final ----------------
// One wave per dst node, lane-transposed: 64 lanes = 4 edge-slots x 16 dim-lanes.
// 8-edge chunks, 2-stage software pipeline. Final write = sc*acc + resid16.
__global__ __launch_bounds__(256) void agg_kernel(const unsigned short* __restrict__ h16,
                                                  const float* __restrict__ el,
                                                  const float* __restrict__ er,
                                                  const int* __restrict__ row_start,
                                                  const int* __restrict__ esrc,
                                                  const unsigned short* __restrict__ resid16,
                                                  float* __restrict__ out, int N) {
    int wid = threadIdx.x >> 6, lane = threadIdx.x & 63;
    int n = blockIdx.x * 4 + wid;
    if (n >= N) return;
    int es = lane >> 4;        // edge slot 0..3
    int l15 = lane & 15;
    int h = l15 >> 2;          // head owning this lane's 8 dims
    int d0 = l15 * 8;
    int beg = row_start[n], end = row_start[n + 1];
    float erh = er[n * 4 + h];
    float den = 0.f;
    float acc[8];
#pragma unroll
    for (int j = 0; j < 8; j++) acc[j] = 0.f;

    if (beg < end) {
        bool ok0, ok1;
        float ev0, ev1; short8 hv0, hv1;
        {
            int i0 = beg + es, i1 = beg + 4 + es;
            ok0 = i0 < end; ok1 = i1 < end;
            int s0 = esrc[ok0 ? i0 : beg];
            int s1 = esrc[ok1 ? i1 : beg];
            ev0 = el[s0 * 4 + h]; ev1 = el[s1 * 4 + h];
            hv0 = *(const short8*)(h16 + (size_t)s0 * HD + d0);
            hv1 = *(const short8*)(h16 + (size_t)s1 * HD + d0);
        }
        for (int base = beg + 8; base < end; base += 8) {
            int i0 = base + es, i1 = base + 4 + es;
            bool p0 = i0 < end, p1 = i1 < end;
            int t0 = esrc[p0 ? i0 : beg];
            int t1 = esrc[p1 ? i1 : beg];
            float fv0 = el[t0 * 4 + h];
            float fv1 = el[t1 * 4 + h];
            short8 g0 = *(const short8*)(h16 + (size_t)t0 * HD + d0);
            short8 g1 = *(const short8*)(h16 + (size_t)t1 * HD + d0);
            float e0 = ev0 + erh; e0 = (e0 > 0.f) ? e0 : NEG_SLOPE * e0;
            float e1 = ev1 + erh; e1 = (e1 > 0.f) ? e1 : NEG_SLOPE * e1;
            float ex0 = ok0 ? __expf(e0) : 0.f;
            float ex1 = ok1 ? __expf(e1) : 0.f;
            den += ex0 + ex1;
#pragma unroll
            for (int j = 0; j < 8; j++)
                acc[j] += ex0 * bf2f((unsigned short)hv0[j]) +
                          ex1 * bf2f((unsigned short)hv1[j]);
            ok0 = p0; ok1 = p1; ev0 = fv0; ev1 = fv1; hv0 = g0; hv1 = g1;
        }
        float e0 = ev0 + erh; e0 = (e0 > 0.f) ? e0 : NEG_SLOPE * e0;
        float e1 = ev1 + erh; e1 = (e1 > 0.f) ? e1 : NEG_SLOPE * e1;
        float ex0 = ok0 ? __expf(e0) : 0.f;
        float ex1 = ok1 ? __expf(e1) : 0.f;
        den += ex0 + ex1;
#pragma unroll
        for (int j = 0; j < 8; j++)
            acc[j] += ex0 * bf2f((unsigned short)hv0[j]) +
                      ex1 * bf2f((unsigned short)hv1[j]);
    }

    // reduce over the 4 edge slots (lanes differing in bits 4,5)
#pragma unroll
    for (int m = 16; m < 64; m <<= 1) {
        den += __shfl_xor(den, m);
#pragma unroll
        for (int j = 0; j < 8; j++) acc[j] += __shfl_xor(acc[j], m);
    }

    if (es == 0) {
        const unsigned short* rp = resid16 + (size_t)n * HD + d0;
        short8 rv = *(const short8*)rp;
        int indeg = end - beg;
        float sc = (indeg > 0) ? sqrtf((float)indeg) / den : 0.f;
        float o[8];
#pragma unroll
        for (int j = 0; j < 8; j++)
            o[j] = sc * acc[j] + bf2f((unsigned short)rv[j]);
        float* op = out + (size_t)n * HD + d0;
        *(float4*)op = make_float4(o[0], o[1], o[2], o[3]);
        *(float4*)(op + 4) = make_float4(o[4], o[5], o[6], o[7]);
    }
}

extern "C" void kernel_launch(void* const* d_in, const int* in_sizes, int n_in,
                              void* d_out, int out_size, void* d_ws, size_t ws_size,
                              hipStream_t stream) {
    const float* feat   = (const float*)d_in[0];
    const int*   src    = (const int*)d_in[1];
    const int*   dst    = (const int*)d_in[2];
    const float* W_fc   = (const float*)d_in[3];
    const float* attn_l = (const float*)d_in[4];
    const float* attn_r = (const float*)d_in[5];
    const float* W_res  = (const float*)d_in[6];
    float* out = (float*)d_out;

    int N = in_sizes[0] / IN_F;   // 50000
    int E = in_sizes[1];          // 800000
    int nb = (N + 255) / 256;     // 196 (<= 256 for scan3's internal scan)

    size_t off = 0;
    auto alloc = [&](size_t bytes) {
        size_t o = off;
        off = (off + bytes + 255) & ~(size_t)255;
        return o;
    };
    char* ws = (char*)d_ws;
    unsigned short* h16     = (unsigned short*)(ws + alloc((size_t)N * HD * 2));
    unsigned short* resid16 = (unsigned short*)(ws + alloc((size_t)N * HD * 2));
    __hip_bfloat16* w16     = (__hip_bfloat16*)(ws + alloc((size_t)2 * HD * IN_F * 2));
    unsigned short* ew16    = (unsigned short*)(ws + alloc((size_t)16 * IN_F * 2));
    float* el               = (float*)(ws + alloc((size_t)N * 4 * 4));
    float* er               = (float*)(ws + alloc((size_t)N * 4 * 4));
    int* out_cnt            = (int*)(ws + alloc((size_t)N * 4));
    int* deg                = (int*)(ws + alloc((size_t)N * 4));
    int* row_start          = (int*)(ws + alloc((size_t)(N + 1) * 4));
    int* bsum               = (int*)(ws + alloc((size_t)nb * 4));
    int* tilectr            = (int*)(ws + alloc(256));
    int* esrc               = (int*)(ws + alloc((size_t)E * 4));
    unsigned short* pc_src  = (unsigned short*)(ws + alloc((size_t)CSRC * N * 2));

    // runtime-adaptive dst-chunk count (each chunk = one uint16 row of N)
    size_t per_chunk = (size_t)2 * N;
    size_t avail = (ws_size > off + 4096) ? (ws_size - off - 4096) : 0;
    int C = (int)(avail / per_chunk);
    if (C > 128) C = 128;         // must stay <= GGRID
    if (C < 32) C = 32;
    unsigned short* pc_dst = (unsigned short*)(ws + alloc((size_t)C * N * 2));
    int chunk = (E + C - 1) / C;
    int chunk_s = (E + CSRC - 1) / CSRC;

    int n4each = HD * IN_F / 4;
    int cvtb = (2 * n4each + 1023) / 1024;     // 16

    hist_cvt_kernel<<<C + CSRC + 1 + cvtb, 1024, 0, stream>>>(
        src, dst, pc_src, pc_dst,
        (const float4*)W_fc, (const float4*)W_res, W_fc, attn_l, attn_r,
        (ushort4*)w16, ew16, n4each, N, E, C, chunk, chunk_s);

    sum_scan1_kernel<<<nb, 256, 0, stream>>>(pc_src, pc_dst, out_cnt, deg, bsum, N, C);
    scan3_kernel<<<nb, 256, 0, stream>>>(deg, bsum, row_start, tilectr, N, nb, E);

    int ntiles = (N + 31) / 32;
    place_gemm_kernel<<<GGRID, 1024, 0, stream>>>(
        src, dst, pc_dst, row_start, esrc,
        feat, (const __hip_bfloat16*)w16, (const __hip_bfloat16*)ew16, out_cnt,
        h16, resid16, el, er, tilectr, N, E, C, chunk, ntiles);

    int nb4 = (N + 3) / 4;
    agg_kernel<<<nb4, 256, 0, stream>>>(h16, el, er, row_start, esrc, resid16, out, N);
}